// Round 1
// baseline (266.649 us; speedup 1.0000x reference)
//
#include <hip/hip_runtime.h>
#include <stdint.h>

// Problem constants
#define B_ 4
#define C_ 256
#define N_ 4096
#define H_ 4
#define DH_ 64
#define BH_ 16   // B_*H_

typedef __bf16 bf16x8 __attribute__((ext_vector_type(8)));
typedef __bf16 bf16x4 __attribute__((ext_vector_type(4)));
typedef float  f32x4  __attribute__((ext_vector_type(4)));
typedef unsigned short u16;

__device__ __forceinline__ u16 f2bf(float f) {
  uint32_t u = __float_as_uint(f);
  return (u16)((u + 0x7FFFu + ((u >> 16) & 1u)) >> 16);  // RNE
}

__device__ __forceinline__ f32x4 mfma16(bf16x8 a, bf16x8 b, f32x4 c) {
  // D[16x16] = A[16x32] @ B[32x16] + C ; fp32 accum
  return __builtin_amdgcn_mfma_f32_16x16x32_bf16(a, b, c, 0, 0, 0);
}

// ---------------- 1. BN statistics -> per-channel a (scale), bb (shift) ----
__global__ __launch_bounds__(256) void k_bnstats(const float* __restrict__ x,
    const float* __restrict__ bw, const float* __restrict__ bbias,
    float* __restrict__ a, float* __restrict__ bb) {
  int ch = blockIdx.x, t = threadIdx.x;
  float s1 = 0.f, s2 = 0.f;
  for (int b = 0; b < B_; ++b) {
    const float4* p = (const float4*)(x + ((size_t)b * C_ + ch) * N_);
    for (int i = t; i < N_ / 4; i += 256) {
      float4 v = p[i];
      s1 += v.x + v.y + v.z + v.w;
      s2 += v.x * v.x + v.y * v.y + v.z * v.z + v.w * v.w;
    }
  }
  for (int off = 32; off; off >>= 1) { s1 += __shfl_down(s1, off); s2 += __shfl_down(s2, off); }
  __shared__ float r1[4], r2[4];
  int w = t >> 6;
  if ((t & 63) == 0) { r1[w] = s1; r2[w] = s2; }
  __syncthreads();
  if (t == 0) {
    s1 = r1[0] + r1[1] + r1[2] + r1[3];
    s2 = r2[0] + r2[1] + r2[2] + r2[3];
    const float inv = 1.f / (B_ * N_);
    float mean = s1 * inv;
    float var  = s2 * inv - mean * mean;       // ddof=0, matches jnp.var
    float av = bw[ch] * rsqrtf(var + 1e-5f);
    a[ch] = av;
    bb[ch] = bbias[ch] - mean * av;
  }
}

// ---------------- 2. Fold BN into weights: wqf = wq*a (bf16), qb = wq@bb ----
__global__ __launch_bounds__(256) void k_fold(const float* __restrict__ wq,
    const float* __restrict__ wo, const float* __restrict__ a, const float* __restrict__ bb,
    u16* __restrict__ wqf, float* __restrict__ qb, u16* __restrict__ woh) {
  int o = blockIdx.x, t = threadIdx.x;
  if (o < 3 * C_) {
    float w = wq[o * C_ + t];
    wqf[o * C_ + t] = f2bf(w * a[t]);
    float contrib = w * bb[t];
    for (int off = 32; off; off >>= 1) contrib += __shfl_down(contrib, off);
    __shared__ float r[4];
    if ((t & 63) == 0) r[t >> 6] = contrib;
    __syncthreads();
    if (t == 0) qb[o] = r[0] + r[1] + r[2] + r[3];
  } else {
    int oo = o - 3 * C_;
    woh[oo * C_ + t] = f2bf(wo[oo * C_ + t]);
  }
}

// ---------------- 3. Transpose x[b][c][n] fp32 -> xT[b][n][c] bf16 ---------
__global__ __launch_bounds__(256) void k_transpose(const float* __restrict__ x,
                                                   u16* __restrict__ xT) {
  __shared__ float tile[64][65];
  int nb = blockIdx.x * 64, cb = blockIdx.y * 64, b = blockIdx.z;
  int t = threadIdx.x;
  int col = t & 63, rq = t >> 6;
  #pragma unroll
  for (int it = 0; it < 16; ++it) {
    int r = it * 4 + rq;  // c-local
    tile[r][col] = x[((size_t)b * C_ + cb + r) * N_ + nb + col];
  }
  __syncthreads();
  #pragma unroll
  for (int it = 0; it < 16; ++it) {
    int r = it * 4 + rq;  // n-local
    xT[((size_t)b * N_ + nb + r) * C_ + cb + col] = f2bf(tile[col][r]);
  }
}

// ---------------- 4. QKV GEMM: [n x o] = xT[n][c] @ wqf[o][c]^T ------------
// 128x128 tile, BK=64, 4 waves (2x2), each wave 64x64 = 4x4 MFMA frags.
// LDS rows are 128B with XOR-16B swizzle: phys = L ^ ((row&7)<<4).
__global__ __launch_bounds__(256) void k_qkvgemm(const u16* __restrict__ xT,
    const u16* __restrict__ wqf, const float* __restrict__ qb,
    u16* __restrict__ q, u16* __restrict__ kk, u16* __restrict__ vtt) {
  __shared__ __align__(16) u16 As[128 * 64];
  __shared__ __align__(16) u16 Bs[128 * 64];
  int b = blockIdx.y;
  int bx = blockIdx.x;
  int mt = bx % 32, ot = bx / 32;
  int mbase = mt * 128, obase = ot * 128;
  int tid = threadIdx.x, w = tid >> 6, lane = tid & 63, lg = lane >> 4, lr = lane & 15;
  int wm = w >> 1, wn = w & 1;
  f32x4 acc[4][4] = {};
  const char* asrc = (const char*)xT + ((size_t)b * N_ + mbase) * 512;  // row stride 512B
  const char* bsrc = (const char*)wqf + (size_t)obase * 512;

  for (int ks = 0; ks < 4; ++ks) {
    int kbase = ks * 64;
    #pragma unroll
    for (int rr = 0; rr < 4; ++rr) {
      int p = tid * 16 + rr * 4096;
      int row = p >> 7, col = p & 127;
      int phys = p ^ ((row & 7) << 4);
      *(bf16x8*)((char*)As + phys) = *(const bf16x8*)(asrc + (size_t)row * 512 + kbase * 2 + col);
      *(bf16x8*)((char*)Bs + phys) = *(const bf16x8*)(bsrc + (size_t)row * 512 + kbase * 2 + col);
    }
    __syncthreads();
    #pragma unroll
    for (int kc = 0; kc < 2; ++kc) {
      bf16x8 af[4], bfr[4];
      #pragma unroll
      for (int i = 0; i < 4; ++i) {
        int r = wm * 64 + i * 16 + lr;
        int L = r * 128 + kc * 64 + lg * 16;
        af[i] = *(const bf16x8*)((const char*)As + (L ^ ((r & 7) << 4)));
        int rb = wn * 64 + i * 16 + lr;
        int Lb = rb * 128 + kc * 64 + lg * 16;
        bfr[i] = *(const bf16x8*)((const char*)Bs + (Lb ^ ((rb & 7) << 4)));
      }
      #pragma unroll
      for (int i = 0; i < 4; ++i)
        #pragma unroll
        for (int jj = 0; jj < 4; ++jj)
          acc[i][jj] = mfma16(af[i], bfr[jj], acc[i][jj]);
    }
    __syncthreads();
  }

  // epilogue: split q/k/v.  o = obase + wn*64 + jj*16 + lr
  int s_id = (obase + wn * 64) >> 8;        // 0=q 1=k 2=v (uniform per wave)
  int h = ((obase + wn * 64) >> 6) & 3;     // uniform per wave
  int bh = b * H_ + h;
  float scale = (s_id == 0) ? 0.125f : 1.f; // d^-0.5, d=64
  #pragma unroll
  for (int i = 0; i < 4; ++i) {
    int n0 = mbase + wm * 64 + i * 16 + lg * 4;
    #pragma unroll
    for (int jj = 0; jj < 4; ++jj) {
      int o = obase + wn * 64 + jj * 16 + lr;
      int dd = jj * 16 + lr;
      float bias = qb[o];
      if (s_id == 2) {
        ushort4 pk;
        pk.x = f2bf(acc[i][jj][0] + bias);
        pk.y = f2bf(acc[i][jj][1] + bias);
        pk.z = f2bf(acc[i][jj][2] + bias);
        pk.w = f2bf(acc[i][jj][3] + bias);
        *(ushort4*)(vtt + ((size_t)bh * DH_ + dd) * N_ + n0) = pk;
      } else {
        u16* dst = (s_id == 0 ? q : kk) + (size_t)bh * N_ * DH_;
        #pragma unroll
        for (int r2 = 0; r2 < 4; ++r2)
          dst[(size_t)(n0 + r2) * DH_ + dd] = f2bf((acc[i][jj][r2] + bias) * scale);
      }
    }
  }
}

// ---------------- 5. Flash attention ---------------------------------------
// block = 64 q-rows (4 waves x 16), KV tiles of 64. q[bh][n][64] (pre-scaled),
// k[bh][n][64], vt[bh][64][n], all bf16. Online softmax fp32.
__global__ __launch_bounds__(256) void k_attn(const u16* __restrict__ q,
    const u16* __restrict__ k, const u16* __restrict__ vt, u16* __restrict__ ao) {
  __shared__ __align__(16) u16 kt_s[64 * 64];     // swizzled [key][d]
  __shared__ __align__(16) u16 vt_s[64 * 64];     // swizzled [d][key]
  __shared__ __align__(16) u16 p_s[4][16 * 68];   // per-wave P, row stride 68 elems
  int bh = blockIdx.y;
  int qbase = blockIdx.x * 64;
  int tid = threadIdx.x, w = tid >> 6, lane = tid & 63, lg = lane >> 4, lr = lane & 15;

  const size_t qoff = ((size_t)bh * N_ + qbase + w * 16 + lr) * DH_;
  bf16x8 aq0 = *(const bf16x8*)(q + qoff + lg * 8);
  bf16x8 aq1 = *(const bf16x8*)(q + qoff + 32 + lg * 8);

  f32x4 Oacc[4] = {};
  float mreg[4] = {-1e30f, -1e30f, -1e30f, -1e30f};
  float lreg[4] = {0.f, 0.f, 0.f, 0.f};

  const u16* kg = k + (size_t)bh * N_ * DH_;
  const u16* vg = vt + (size_t)bh * DH_ * N_;
  u16* pw = p_s[w];

  for (int kt = 0; kt < N_ / 64; ++kt) {
    // stage K (contiguous 8KB) and V^T (64 rows x 128B) with write-side swizzle
    #pragma unroll
    for (int rr = 0; rr < 2; ++rr) {
      int p = tid * 16 + rr * 4096;
      int row = p >> 7, col = p & 127;
      int phys = p ^ ((row & 7) << 4);
      *(bf16x8*)((char*)kt_s + phys) =
          *(const bf16x8*)((const char*)(kg + (size_t)kt * 4096) + p);
      *(bf16x8*)((char*)vt_s + phys) =
          *(const bf16x8*)((const char*)vg + (size_t)row * 8192 + kt * 128 + col);
    }
    __syncthreads();

    // S[16 x 64] = Q @ K^T  (4 key sub-tiles of 16)
    f32x4 s[4];
    #pragma unroll
    for (int t4 = 0; t4 < 4; ++t4) {
      s[t4] = f32x4{0.f, 0.f, 0.f, 0.f};
      int key = t4 * 16 + lr;
      int L0 = key * 128 + lg * 16;
      int L1 = key * 128 + 64 + lg * 16;
      bf16x8 bk0 = *(const bf16x8*)((const char*)kt_s + (L0 ^ ((key & 7) << 4)));
      bf16x8 bk1 = *(const bf16x8*)((const char*)kt_s + (L1 ^ ((key & 7) << 4)));
      s[t4] = mfma16(aq0, bk0, s[t4]);
      s[t4] = mfma16(aq1, bk1, s[t4]);
    }

    // online softmax; lane's row j is (lg*4+j); 16-lane butterfly per row
    float al[4];
    #pragma unroll
    for (int j = 0; j < 4; ++j) {
      float mx = fmaxf(fmaxf(s[0][j], s[1][j]), fmaxf(s[2][j], s[3][j]));
      #pragma unroll
      for (int off = 1; off < 16; off <<= 1) mx = fmaxf(mx, __shfl_xor(mx, off));
      float mn = fmaxf(mreg[j], mx);
      al[j] = __expf(mreg[j] - mn);
      mreg[j] = mn;
      float sum = 0.f;
      #pragma unroll
      for (int t4 = 0; t4 < 4; ++t4) {
        float pv = __expf(s[t4][j] - mn);
        s[t4][j] = pv;
        sum += pv;
      }
      #pragma unroll
      for (int off = 1; off < 16; off <<= 1) sum += __shfl_xor(sum, off);
      lreg[j] = lreg[j] * al[j] + sum;
    }
    #pragma unroll
    for (int t4 = 0; t4 < 4; ++t4)
      #pragma unroll
      for (int j = 0; j < 4; ++j) Oacc[t4][j] *= al[j];

    // P -> LDS (C-layout row lg*4+j, key t*16+lr), stride 68 elems (136B)
    #pragma unroll
    for (int t4 = 0; t4 < 4; ++t4)
      #pragma unroll
      for (int j = 0; j < 4; ++j)
        pw[(lg * 4 + j) * 68 + t4 * 16 + lr] = f2bf(s[t4][j]);
    __syncthreads();  // cross-lane P visibility (conservative)

    // O += P @ V : A-frag = P rows (lane&15), B-frag = V^T contiguous keys
    #pragma unroll
    for (int kc = 0; kc < 2; ++kc) {
      const char* pb = (const char*)pw + lr * 136 + kc * 64 + lg * 16;
      bf16x4 plo = *(const bf16x4*)pb;
      bf16x4 phi = *(const bf16x4*)(pb + 8);
      bf16x8 pa = __builtin_shufflevector(plo, phi, 0, 1, 2, 3, 4, 5, 6, 7);
      #pragma unroll
      for (int t4 = 0; t4 < 4; ++t4) {
        int d = t4 * 16 + lr;
        int L = d * 128 + kc * 64 + lg * 16;
        bf16x8 bv = *(const bf16x8*)((const char*)vt_s + (L ^ ((d & 7) << 4)));
        Oacc[t4] = mfma16(pa, bv, Oacc[t4]);
      }
    }
    __syncthreads();  // before next stage overwrites tiles
  }

  // epilogue: normalize and store ao[bh][qrow][d] bf16
  size_t aobase = ((size_t)bh * N_ + qbase + w * 16) * DH_;
  #pragma unroll
  for (int t4 = 0; t4 < 4; ++t4)
    #pragma unroll
    for (int j = 0; j < 4; ++j) {
      float v = Oacc[t4][j] / lreg[j];
      ao[aobase + (size_t)(lg * 4 + j) * DH_ + t4 * 16 + lr] = f2bf(v);
    }
}

// ---------------- 6. Output GEMM: out[b][o][i] = wo[o][c'] @ ao + b_out ----
__global__ __launch_bounds__(256) void k_outgemm(const u16* __restrict__ ao,
    const u16* __restrict__ woh, const float* __restrict__ b_out,
    float* __restrict__ out) {
  __shared__ __align__(16) u16 As[128 * 64];
  __shared__ __align__(16) u16 Bs[128 * 64];
  int b = blockIdx.y;
  int bx = blockIdx.x;
  int mt = bx & 31, ot = bx >> 5;
  int mbase = mt * 128, obase = ot * 128;
  int tid = threadIdx.x, w = tid >> 6, lane = tid & 63, lg = lane >> 4, lr = lane & 15;
  int wm = w >> 1, wn = w & 1;
  f32x4 acc[4][4] = {};
  const char* bsrc = (const char*)woh + (size_t)obase * 512;

  for (int ks = 0; ks < 4; ++ks) {
    int kbase = ks * 64;
    int h = kbase >> 6;
    const char* asrc = (const char*)ao + ((size_t)(b * H_ + h) * N_ + mbase) * 128;
    #pragma unroll
    for (int rr = 0; rr < 4; ++rr) {
      int p = tid * 16 + rr * 4096;
      int row = p >> 7, col = p & 127;
      int phys = p ^ ((row & 7) << 4);
      *(bf16x8*)((char*)As + phys) = *(const bf16x8*)(asrc + p);  // tile is contiguous
      *(bf16x8*)((char*)Bs + phys) = *(const bf16x8*)(bsrc + (size_t)row * 512 + kbase * 2 + col);
    }
    __syncthreads();
    #pragma unroll
    for (int kc = 0; kc < 2; ++kc) {
      bf16x8 af[4], bfr[4];
      #pragma unroll
      for (int i = 0; i < 4; ++i) {
        int r = wm * 64 + i * 16 + lr;
        int L = r * 128 + kc * 64 + lg * 16;
        af[i] = *(const bf16x8*)((const char*)As + (L ^ ((r & 7) << 4)));
        int rb = wn * 64 + i * 16 + lr;
        int Lb = rb * 128 + kc * 64 + lg * 16;
        bfr[i] = *(const bf16x8*)((const char*)Bs + (Lb ^ ((rb & 7) << 4)));
      }
      #pragma unroll
      for (int i = 0; i < 4; ++i)
        #pragma unroll
        for (int jj = 0; jj < 4; ++jj)
          acc[i][jj] = mfma16(af[i], bfr[jj], acc[i][jj]);
    }
    __syncthreads();
  }

  #pragma unroll
  for (int i = 0; i < 4; ++i) {
    int n0 = mbase + wm * 64 + i * 16 + lg * 4;
    #pragma unroll
    for (int jj = 0; jj < 4; ++jj) {
      int o = obase + wn * 64 + jj * 16 + lr;
      float bias = b_out[o];
      float4 vv = make_float4(acc[i][jj][0] + bias, acc[i][jj][1] + bias,
                              acc[i][jj][2] + bias, acc[i][jj][3] + bias);
      *(float4*)(out + ((size_t)(b * C_ + o)) * N_ + n0) = vv;
    }
  }
}

// ---------------- launch ----------------------------------------------------
extern "C" void kernel_launch(void* const* d_in, const int* in_sizes, int n_in,
                              void* d_out, int out_size, void* d_ws, size_t ws_size,
                              hipStream_t stream) {
  const float* x    = (const float*)d_in[0];
  const float* bnw  = (const float*)d_in[1];
  const float* bnb  = (const float*)d_in[2];
  const float* wqkv = (const float*)d_in[3];
  const float* wout = (const float*)d_in[4];
  const float* bout = (const float*)d_in[5];
  float* out = (float*)d_out;
  char* ws = (char*)d_ws;

  // workspace layout (bytes)
  float* a   = (float*)(ws + 0);        // 256 f32
  float* bb  = (float*)(ws + 1024);     // 256 f32
  float* qb  = (float*)(ws + 2048);     // 768 f32
  u16* wqf = (u16*)(ws + 8192);                        // 768x256 bf16
  u16* woh = (u16*)(ws + 8192 + 393216);               // 256x256 bf16
  const size_t big = 8388608;                           // 8 MiB chunks
  u16* xT  = (u16*)(ws + 532480);                      // [4][4096][256] bf16
  u16* q   = (u16*)(ws + 532480 + 1 * big);            // [16][4096][64] bf16
  u16* kk  = (u16*)(ws + 532480 + 2 * big);            // [16][4096][64] bf16
  u16* vt  = (u16*)(ws + 532480 + 3 * big);            // [16][64][4096] bf16
  u16* ao  = (u16*)(ws + 532480 + 4 * big);            // [16][4096][64] bf16

  k_bnstats  <<<256, 256, 0, stream>>>(x, bnw, bnb, a, bb);
  k_fold     <<<1024, 256, 0, stream>>>(wqkv, wout, a, bb, wqf, qb, woh);
  k_transpose<<<dim3(64, 4, 4), 256, 0, stream>>>(x, xT);
  k_qkvgemm  <<<dim3(192, 4), 256, 0, stream>>>(xT, wqf, qb, q, kk, vt);
  k_attn     <<<dim3(64, 16), 256, 0, stream>>>(q, kk, vt, ao);
  k_outgemm  <<<dim3(64, 4), 256, 0, stream>>>(ao, woh, bout, out);
}

// Round 2
// 195.190 us; speedup vs baseline: 1.3661x; 1.3661x over previous
//
#include <hip/hip_runtime.h>
#include <stdint.h>

// Problem constants
#define B_ 4
#define C_ 256
#define N_ 4096
#define H_ 4
#define DH_ 64
#define BH_ 16   // B_*H_

typedef __bf16 bf16x8 __attribute__((ext_vector_type(8)));
typedef __bf16 bf16x4 __attribute__((ext_vector_type(4)));
typedef float  f32x4  __attribute__((ext_vector_type(4)));
typedef float  f32x16 __attribute__((ext_vector_type(16)));
typedef unsigned short u16;

__device__ __forceinline__ u16 f2bf(float f) {
  uint32_t u = __float_as_uint(f);
  return (u16)((u + 0x7FFFu + ((u >> 16) & 1u)) >> 16);  // RNE
}

__device__ __forceinline__ f32x4 mfma16(bf16x8 a, bf16x8 b, f32x4 c) {
  return __builtin_amdgcn_mfma_f32_16x16x32_bf16(a, b, c, 0, 0, 0);
}
__device__ __forceinline__ f32x16 mfma32(bf16x8 a, bf16x8 b, f32x16 c) {
  return __builtin_amdgcn_mfma_f32_32x32x16_bf16(a, b, c, 0, 0, 0);
}
__device__ __forceinline__ unsigned pk2(float a, float b) {
  unsigned r;
  asm("v_cvt_pk_bf16_f32 %0, %1, %2" : "=v"(r) : "v"(a), "v"(b));
  return r;
}

// ---------------- 1. BN statistics -> per-channel a (scale), bb (shift) ----
__global__ __launch_bounds__(256) void k_bnstats(const float* __restrict__ x,
    const float* __restrict__ bw, const float* __restrict__ bbias,
    float* __restrict__ a, float* __restrict__ bb) {
  int ch = blockIdx.x, t = threadIdx.x;
  float s1 = 0.f, s2 = 0.f;
  for (int b = 0; b < B_; ++b) {
    const float4* p = (const float4*)(x + ((size_t)b * C_ + ch) * N_);
    for (int i = t; i < N_ / 4; i += 256) {
      float4 v = p[i];
      s1 += v.x + v.y + v.z + v.w;
      s2 += v.x * v.x + v.y * v.y + v.z * v.z + v.w * v.w;
    }
  }
  for (int off = 32; off; off >>= 1) { s1 += __shfl_down(s1, off); s2 += __shfl_down(s2, off); }
  __shared__ float r1[4], r2[4];
  int w = t >> 6;
  if ((t & 63) == 0) { r1[w] = s1; r2[w] = s2; }
  __syncthreads();
  if (t == 0) {
    s1 = r1[0] + r1[1] + r1[2] + r1[3];
    s2 = r2[0] + r2[1] + r2[2] + r2[3];
    const float inv = 1.f / (B_ * N_);
    float mean = s1 * inv;
    float var  = s2 * inv - mean * mean;
    float av = bw[ch] * rsqrtf(var + 1e-5f);
    a[ch] = av;
    bb[ch] = bbias[ch] - mean * av;
  }
}

// ---------------- 2. Fold BN into weights ----------------------------------
__global__ __launch_bounds__(256) void k_fold(const float* __restrict__ wq,
    const float* __restrict__ wo, const float* __restrict__ a, const float* __restrict__ bb,
    u16* __restrict__ wqf, float* __restrict__ qb, u16* __restrict__ woh) {
  int o = blockIdx.x, t = threadIdx.x;
  if (o < 3 * C_) {
    float w = wq[o * C_ + t];
    wqf[o * C_ + t] = f2bf(w * a[t]);
    float contrib = w * bb[t];
    for (int off = 32; off; off >>= 1) contrib += __shfl_down(contrib, off);
    __shared__ float r[4];
    if ((t & 63) == 0) r[t >> 6] = contrib;
    __syncthreads();
    if (t == 0) qb[o] = r[0] + r[1] + r[2] + r[3];
  } else {
    int oo = o - 3 * C_;
    woh[oo * C_ + t] = f2bf(wo[oo * C_ + t]);
  }
}

// ---------------- 3. Transpose x[b][c][n] fp32 -> xT[b][n][c] bf16 ---------
__global__ __launch_bounds__(256) void k_transpose(const float* __restrict__ x,
                                                   u16* __restrict__ xT) {
  __shared__ float tile[64][65];
  int nb = blockIdx.x * 64, cb = blockIdx.y * 64, b = blockIdx.z;
  int t = threadIdx.x;
  int col = t & 63, rq = t >> 6;
  #pragma unroll
  for (int it = 0; it < 16; ++it) {
    int r = it * 4 + rq;
    tile[r][col] = x[((size_t)b * C_ + cb + r) * N_ + nb + col];
  }
  __syncthreads();
  #pragma unroll
  for (int it = 0; it < 16; ++it) {
    int r = it * 4 + rq;
    xT[((size_t)b * N_ + nb + r) * C_ + cb + col] = f2bf(tile[col][r]);
  }
}

// ---------------- 4. QKV GEMM ----------------------------------------------
// q is pre-scaled by d^-0.5 * log2(e) so attention softmax runs in exp2 domain.
__global__ __launch_bounds__(256) void k_qkvgemm(const u16* __restrict__ xT,
    const u16* __restrict__ wqf, const float* __restrict__ qb,
    u16* __restrict__ q, u16* __restrict__ kk, u16* __restrict__ vtt) {
  __shared__ __align__(16) u16 As[128 * 64];
  __shared__ __align__(16) u16 Bs[128 * 64];
  int b = blockIdx.y;
  int bx = blockIdx.x;
  int mt = bx % 32, ot = bx / 32;
  int mbase = mt * 128, obase = ot * 128;
  int tid = threadIdx.x, w = tid >> 6, lane = tid & 63, lg = lane >> 4, lr = lane & 15;
  int wm = w >> 1, wn = w & 1;
  f32x4 acc[4][4] = {};
  const char* asrc = (const char*)xT + ((size_t)b * N_ + mbase) * 512;
  const char* bsrc = (const char*)wqf + (size_t)obase * 512;

  for (int ks = 0; ks < 4; ++ks) {
    int kbase = ks * 64;
    #pragma unroll
    for (int rr = 0; rr < 4; ++rr) {
      int p = tid * 16 + rr * 4096;
      int row = p >> 7, col = p & 127;
      int phys = p ^ ((row & 7) << 4);
      *(bf16x8*)((char*)As + phys) = *(const bf16x8*)(asrc + (size_t)row * 512 + kbase * 2 + col);
      *(bf16x8*)((char*)Bs + phys) = *(const bf16x8*)(bsrc + (size_t)row * 512 + kbase * 2 + col);
    }
    __syncthreads();
    #pragma unroll
    for (int kc = 0; kc < 2; ++kc) {
      bf16x8 af[4], bfr[4];
      #pragma unroll
      for (int i = 0; i < 4; ++i) {
        int r = wm * 64 + i * 16 + lr;
        int L = r * 128 + kc * 64 + lg * 16;
        af[i] = *(const bf16x8*)((const char*)As + (L ^ ((r & 7) << 4)));
        int rb = wn * 64 + i * 16 + lr;
        int Lb = rb * 128 + kc * 64 + lg * 16;
        bfr[i] = *(const bf16x8*)((const char*)Bs + (Lb ^ ((rb & 7) << 4)));
      }
      #pragma unroll
      for (int i = 0; i < 4; ++i)
        #pragma unroll
        for (int jj = 0; jj < 4; ++jj)
          acc[i][jj] = mfma16(af[i], bfr[jj], acc[i][jj]);
    }
    __syncthreads();
  }

  int s_id = (obase + wn * 64) >> 8;
  int h = ((obase + wn * 64) >> 6) & 3;
  int bh = b * H_ + h;
  // d^-0.5 * log2(e): softmax in exp2 domain
  float scale = (s_id == 0) ? 0.18033688011112042f : 1.f;
  #pragma unroll
  for (int i = 0; i < 4; ++i) {
    int n0 = mbase + wm * 64 + i * 16 + lg * 4;
    #pragma unroll
    for (int jj = 0; jj < 4; ++jj) {
      int o = obase + wn * 64 + jj * 16 + lr;
      int dd = jj * 16 + lr;
      float bias = qb[o];
      if (s_id == 2) {
        ushort4 pk;
        pk.x = f2bf(acc[i][jj][0] + bias);
        pk.y = f2bf(acc[i][jj][1] + bias);
        pk.z = f2bf(acc[i][jj][2] + bias);
        pk.w = f2bf(acc[i][jj][3] + bias);
        *(ushort4*)(vtt + ((size_t)bh * DH_ + dd) * N_ + n0) = pk;
      } else {
        u16* dst = (s_id == 0 ? q : kk) + (size_t)bh * N_ * DH_;
        #pragma unroll
        for (int r2 = 0; r2 < 4; ++r2)
          dst[(size_t)(n0 + r2) * DH_ + dd] = f2bf((acc[i][jj][r2] + bias) * scale);
      }
    }
  }
}

// ---------------- 5. Flash attention (32x32 MFMA, swapped operands) --------
// Block: 256 q-rows = 4 waves x (2 qgroups x 32 rows). KV tile = 64.
// S^T = mfma(K, Q): lane owns q=lane&31, keys=crow(r,hi) -> lane-local softmax.
// O^T = mfma(V^T, P^T): rescale + epilogue also lane-local in q.
__device__ __forceinline__ void stage_tile(const char* kg_t, const char* vg_bh, int kt,
                                           char* kbuf, char* vbuf, int w, int lane) {
  #pragma unroll
  for (int i = 0; i < 2; ++i) {
    int poff = w * 2048 + i * 1024 + lane * 16;      // phys byte in 8KB tile
    int L = poff ^ (((poff >> 7) & 7) << 4);         // logical byte (involution)
    // K tile: contiguous [64 keys][64 c] bf16 = 8KB
    __builtin_amdgcn_global_load_lds(
        (const __attribute__((address_space(1))) void*)(kg_t + (size_t)kt * 8192 + L),
        (__attribute__((address_space(3))) void*)(kbuf + w * 2048 + i * 1024), 16, 0, 0);
    // V^T tile: row d stride 8192B, 128B per row
    int d = L >> 7, col = L & 127;
    __builtin_amdgcn_global_load_lds(
        (const __attribute__((address_space(1))) void*)(vg_bh + (size_t)d * 8192 + (size_t)kt * 128 + col),
        (__attribute__((address_space(3))) void*)(vbuf + w * 2048 + i * 1024), 16, 0, 0);
  }
}

__global__ __launch_bounds__(256, 1) void k_attn(const u16* __restrict__ q,
    const u16* __restrict__ k, const u16* __restrict__ vt, u16* __restrict__ ao) {
  __shared__ __align__(16) char kt_s[2][8192];
  __shared__ __align__(16) char vt_s[2][8192];
  int id = blockIdx.x;
  int xcd = id & 7, j = id >> 3;
  int bh = xcd * 2 + (j & 1);      // same-bh blocks share an XCD (KV L2-resident)
  int qbase = (j >> 1) * 256;
  int tid = threadIdx.x, w = tid >> 6, lane = tid & 63;
  int l31 = lane & 31, hi = lane >> 5;

  const char* kg_t = (const char*)(k + (size_t)bh * N_ * DH_);
  const char* vg_bh = (const char*)(vt + (size_t)bh * DH_ * N_);

  // Q B-frags (held in regs): bq[qg][cc]: Q[q=l31][c=cc*16+hi*8 ..+7]
  bf16x8 bq[2][4];
  #pragma unroll
  for (int qg = 0; qg < 2; ++qg) {
    const u16* qp = q + ((size_t)bh * N_ + qbase + w * 64 + qg * 32 + l31) * DH_;
    #pragma unroll
    for (int cc = 0; cc < 4; ++cc)
      bq[qg][cc] = *(const bf16x8*)(qp + cc * 16 + hi * 8);
  }

  f32x16 Oacc[2][2];
  #pragma unroll
  for (int qg = 0; qg < 2; ++qg)
    #pragma unroll
    for (int dt = 0; dt < 2; ++dt)
      #pragma unroll
      for (int i = 0; i < 16; ++i) Oacc[qg][dt][i] = 0.f;
  float m[2] = {-1e30f, -1e30f}, l[2] = {0.f, 0.f};

  stage_tile(kg_t, vg_bh, 0, kt_s[0], vt_s[0], w, lane);
  int cur = 0;
  for (int kt = 0; kt < N_ / 64; ++kt) {
    __syncthreads();   // drains vmcnt(0): staged tile visible; prev reads done
    if (kt + 1 < N_ / 64)
      stage_tile(kg_t, vg_bh, kt + 1, kt_s[cur ^ 1], vt_s[cur ^ 1], w, lane);

    const char* kb = kt_s[cur];
    const char* vb = vt_s[cur];
    // K frags: A[key=kt2*32+l31][c=cc*16+hi*8..]
    bf16x8 kf[2][4], vf[2][4];
    #pragma unroll
    for (int kt2 = 0; kt2 < 2; ++kt2) {
      int row = kt2 * 32 + l31; int sw = (row & 7) << 4; int rb = row * 128;
      #pragma unroll
      for (int cc = 0; cc < 4; ++cc)
        kf[kt2][cc] = *(const bf16x8*)(kb + ((rb + cc * 32 + hi * 16) ^ sw));
    }
    // V^T frags: A[d=dt*32+l31][key=ks*16+hi*8..]
    #pragma unroll
    for (int dt = 0; dt < 2; ++dt) {
      int row = dt * 32 + l31; int sw = (row & 7) << 4; int rb = row * 128;
      #pragma unroll
      for (int ks = 0; ks < 4; ++ks)
        vf[dt][ks] = *(const bf16x8*)(vb + ((rb + ks * 32 + hi * 16) ^ sw));
    }

    // S^T[key][q] = K @ Q^T  (log2-domain scores)
    f32x16 sA[2][2];
    #pragma unroll
    for (int qg = 0; qg < 2; ++qg)
      #pragma unroll
      for (int kt2 = 0; kt2 < 2; ++kt2)
        #pragma unroll
        for (int i = 0; i < 16; ++i) sA[qg][kt2][i] = 0.f;
    #pragma unroll
    for (int cc = 0; cc < 4; ++cc)
      #pragma unroll
      for (int qg = 0; qg < 2; ++qg)
        #pragma unroll
        for (int kt2 = 0; kt2 < 2; ++kt2)
          sA[qg][kt2] = mfma32(kf[kt2][cc], bq[qg][cc], sA[qg][kt2]);

    #pragma unroll
    for (int qg = 0; qg < 2; ++qg) {
      // lane-local softmax over 32 keys + one cross-half exchange
      float mx = fmaxf(sA[qg][0][0], sA[qg][1][0]);
      #pragma unroll
      for (int i = 1; i < 16; ++i) mx = fmaxf(mx, fmaxf(sA[qg][0][i], sA[qg][1][i]));
      mx = fmaxf(mx, __shfl_xor(mx, 32));
      float mn = fmaxf(m[qg], mx);
      float al = __builtin_amdgcn_exp2f(m[qg] - mn);
      m[qg] = mn;
      float sum = 0.f;
      #pragma unroll
      for (int kt2 = 0; kt2 < 2; ++kt2)
        #pragma unroll
        for (int i = 0; i < 16; ++i) {
          float pv = __builtin_amdgcn_exp2f(sA[qg][kt2][i] - mn);
          sA[qg][kt2][i] = pv;
          sum += pv;
        }
      sum += __shfl_xor(sum, 32);
      l[qg] = l[qg] * al + sum;
      #pragma unroll
      for (int dt = 0; dt < 2; ++dt)
        #pragma unroll
        for (int i = 0; i < 16; ++i) Oacc[qg][dt][i] *= al;

      // P^T B-frags via cvt_pk + permlane32_swap (T12)
      bf16x8 pa[4];
      #pragma unroll
      for (int ks = 0; ks < 4; ++ks) {
        const int kt2 = ks >> 1; const int a0 = 8 * (ks & 1);
        unsigned u0 = pk2(sA[qg][kt2][a0 + 0], sA[qg][kt2][a0 + 1]);
        unsigned u1 = pk2(sA[qg][kt2][a0 + 2], sA[qg][kt2][a0 + 3]);
        unsigned u2 = pk2(sA[qg][kt2][a0 + 4], sA[qg][kt2][a0 + 5]);
        unsigned u3 = pk2(sA[qg][kt2][a0 + 6], sA[qg][kt2][a0 + 7]);
        asm("v_permlane32_swap_b32 %0, %1" : "+v"(u0), "+v"(u2));
        asm("v_permlane32_swap_b32 %0, %1" : "+v"(u1), "+v"(u3));
        union { unsigned u[4]; bf16x8 b; } cv;
        cv.u[0] = u0; cv.u[1] = u1; cv.u[2] = u2; cv.u[3] = u3;
        pa[ks] = cv.b;
      }
      // O^T += V^T @ P^T
      #pragma unroll
      for (int ks = 0; ks < 4; ++ks)
        #pragma unroll
        for (int dt = 0; dt < 2; ++dt)
          Oacc[qg][dt] = mfma32(vf[dt][ks], pa[ks], Oacc[qg][dt]);
    }
    cur ^= 1;
  }

  // epilogue: O^T[d][q] regs -> ao[bh][q][d] bf16
  #pragma unroll
  for (int qg = 0; qg < 2; ++qg) {
    float rl = 1.f / l[qg];
    size_t rowb = ((size_t)bh * N_ + qbase + w * 64 + qg * 32 + l31) * DH_;
    #pragma unroll
    for (int dt = 0; dt < 2; ++dt)
      #pragma unroll
      for (int rq = 0; rq < 4; ++rq) {
        ushort4 pk4;
        pk4.x = f2bf(Oacc[qg][dt][rq * 4 + 0] * rl);
        pk4.y = f2bf(Oacc[qg][dt][rq * 4 + 1] * rl);
        pk4.z = f2bf(Oacc[qg][dt][rq * 4 + 2] * rl);
        pk4.w = f2bf(Oacc[qg][dt][rq * 4 + 3] * rl);
        *(ushort4*)(ao + rowb + dt * 32 + rq * 8 + hi * 4) = pk4;
      }
  }
}

// ---------------- 6. Output GEMM -------------------------------------------
__global__ __launch_bounds__(256) void k_outgemm(const u16* __restrict__ ao,
    const u16* __restrict__ woh, const float* __restrict__ b_out,
    float* __restrict__ out) {
  __shared__ __align__(16) u16 As[128 * 64];
  __shared__ __align__(16) u16 Bs[128 * 64];
  int b = blockIdx.y;
  int bx = blockIdx.x;
  int mt = bx & 31, ot = bx >> 5;
  int mbase = mt * 128, obase = ot * 128;
  int tid = threadIdx.x, w = tid >> 6, lane = tid & 63, lg = lane >> 4, lr = lane & 15;
  int wm = w >> 1, wn = w & 1;
  f32x4 acc[4][4] = {};
  const char* bsrc = (const char*)woh + (size_t)obase * 512;

  for (int ks = 0; ks < 4; ++ks) {
    int kbase = ks * 64;
    int h = kbase >> 6;
    const char* asrc = (const char*)ao + ((size_t)(b * H_ + h) * N_ + mbase) * 128;
    #pragma unroll
    for (int rr = 0; rr < 4; ++rr) {
      int p = tid * 16 + rr * 4096;
      int row = p >> 7, col = p & 127;
      int phys = p ^ ((row & 7) << 4);
      *(bf16x8*)((char*)As + phys) = *(const bf16x8*)(asrc + p);
      *(bf16x8*)((char*)Bs + phys) = *(const bf16x8*)(bsrc + (size_t)row * 512 + kbase * 2 + col);
    }
    __syncthreads();
    #pragma unroll
    for (int kc = 0; kc < 2; ++kc) {
      bf16x8 af[4], bfr[4];
      #pragma unroll
      for (int i = 0; i < 4; ++i) {
        int r = wm * 64 + i * 16 + lr;
        int L = r * 128 + kc * 64 + lg * 16;
        af[i] = *(const bf16x8*)((const char*)As + (L ^ ((r & 7) << 4)));
        int rb = wn * 64 + i * 16 + lr;
        int Lb = rb * 128 + kc * 64 + lg * 16;
        bfr[i] = *(const bf16x8*)((const char*)Bs + (Lb ^ ((rb & 7) << 4)));
      }
      #pragma unroll
      for (int i = 0; i < 4; ++i)
        #pragma unroll
        for (int jj = 0; jj < 4; ++jj)
          acc[i][jj] = mfma16(af[i], bfr[jj], acc[i][jj]);
    }
    __syncthreads();
  }

  #pragma unroll
  for (int i = 0; i < 4; ++i) {
    int n0 = mbase + wm * 64 + i * 16 + lg * 4;
    #pragma unroll
    for (int jj = 0; jj < 4; ++jj) {
      int o = obase + wn * 64 + jj * 16 + lr;
      float bias = b_out[o];
      float4 vv = make_float4(acc[i][jj][0] + bias, acc[i][jj][1] + bias,
                              acc[i][jj][2] + bias, acc[i][jj][3] + bias);
      *(float4*)(out + ((size_t)(b * C_ + o)) * N_ + n0) = vv;
    }
  }
}

// ---------------- launch ----------------------------------------------------
extern "C" void kernel_launch(void* const* d_in, const int* in_sizes, int n_in,
                              void* d_out, int out_size, void* d_ws, size_t ws_size,
                              hipStream_t stream) {
  const float* x    = (const float*)d_in[0];
  const float* bnw  = (const float*)d_in[1];
  const float* bnb  = (const float*)d_in[2];
  const float* wqkv = (const float*)d_in[3];
  const float* wout = (const float*)d_in[4];
  const float* bout = (const float*)d_in[5];
  float* out = (float*)d_out;
  char* ws = (char*)d_ws;

  float* a   = (float*)(ws + 0);
  float* bb  = (float*)(ws + 1024);
  float* qb  = (float*)(ws + 2048);
  u16* wqf = (u16*)(ws + 8192);
  u16* woh = (u16*)(ws + 8192 + 393216);
  const size_t big = 8388608;
  u16* xT  = (u16*)(ws + 532480);
  u16* q   = (u16*)(ws + 532480 + 1 * big);
  u16* kk  = (u16*)(ws + 532480 + 2 * big);
  u16* vt  = (u16*)(ws + 532480 + 3 * big);
  u16* ao  = (u16*)(ws + 532480 + 4 * big);

  k_bnstats  <<<256, 256, 0, stream>>>(x, bnw, bnb, a, bb);
  k_fold     <<<1024, 256, 0, stream>>>(wqkv, wout, a, bb, wqf, qb, woh);
  k_transpose<<<dim3(64, 4, 4), 256, 0, stream>>>(x, xT);
  k_qkvgemm  <<<dim3(192, 4), 256, 0, stream>>>(xT, wqf, qb, q, kk, vt);
  k_attn     <<<dim3(256), 256, 0, stream>>>(q, kk, vt, ao);
  k_outgemm  <<<dim3(64, 4), 256, 0, stream>>>(ao, woh, bout, out);
}

// Round 3
// 141.055 us; speedup vs baseline: 1.8904x; 1.3838x over previous
//
#include <hip/hip_runtime.h>
#include <stdint.h>

// Problem constants
#define B_ 4
#define C_ 256
#define N_ 4096
#define H_ 4
#define DH_ 64
#define BH_ 16   // B_*H_

typedef __bf16 bf16x8 __attribute__((ext_vector_type(8)));
typedef __bf16 bf16x4 __attribute__((ext_vector_type(4)));
typedef float  f32x4  __attribute__((ext_vector_type(4)));
typedef float  f32x16 __attribute__((ext_vector_type(16)));
typedef unsigned short u16;

__device__ __forceinline__ u16 f2bf(float f) {
  uint32_t u = __float_as_uint(f);
  return (u16)((u + 0x7FFFu + ((u >> 16) & 1u)) >> 16);  // RNE
}

__device__ __forceinline__ f32x4 mfma16(bf16x8 a, bf16x8 b, f32x4 c) {
  return __builtin_amdgcn_mfma_f32_16x16x32_bf16(a, b, c, 0, 0, 0);
}
__device__ __forceinline__ f32x16 mfma32(bf16x8 a, bf16x8 b, f32x16 c) {
  return __builtin_amdgcn_mfma_f32_32x32x16_bf16(a, b, c, 0, 0, 0);
}
__device__ __forceinline__ unsigned pk2(float a, float b) {
  unsigned r;
  asm("v_cvt_pk_bf16_f32 %0, %1, %2" : "=v"(r) : "v"(a), "v"(b));
  return r;
}

// ---------------- 1. BN statistics -> per-channel a (scale), bb (shift) ----
__global__ __launch_bounds__(256) void k_bnstats(const float* __restrict__ x,
    const float* __restrict__ bw, const float* __restrict__ bbias,
    float* __restrict__ a, float* __restrict__ bb) {
  int ch = blockIdx.x, t = threadIdx.x;
  float s1 = 0.f, s2 = 0.f;
  for (int b = 0; b < B_; ++b) {
    const float4* p = (const float4*)(x + ((size_t)b * C_ + ch) * N_);
    for (int i = t; i < N_ / 4; i += 256) {
      float4 v = p[i];
      s1 += v.x + v.y + v.z + v.w;
      s2 += v.x * v.x + v.y * v.y + v.z * v.z + v.w * v.w;
    }
  }
  for (int off = 32; off; off >>= 1) { s1 += __shfl_down(s1, off); s2 += __shfl_down(s2, off); }
  __shared__ float r1[4], r2[4];
  int w = t >> 6;
  if ((t & 63) == 0) { r1[w] = s1; r2[w] = s2; }
  __syncthreads();
  if (t == 0) {
    s1 = r1[0] + r1[1] + r1[2] + r1[3];
    s2 = r2[0] + r2[1] + r2[2] + r2[3];
    const float inv = 1.f / (B_ * N_);
    float mean = s1 * inv;
    float var  = s2 * inv - mean * mean;
    float av = bw[ch] * rsqrtf(var + 1e-5f);
    a[ch] = av;
    bb[ch] = bbias[ch] - mean * av;
  }
}

// ---------------- 2. Fold BN into weights ----------------------------------
__global__ __launch_bounds__(256) void k_fold(const float* __restrict__ wq,
    const float* __restrict__ wo, const float* __restrict__ a, const float* __restrict__ bb,
    u16* __restrict__ wqf, float* __restrict__ qb, u16* __restrict__ woh) {
  int o = blockIdx.x, t = threadIdx.x;
  if (o < 3 * C_) {
    float w = wq[o * C_ + t];
    wqf[o * C_ + t] = f2bf(w * a[t]);
    float contrib = w * bb[t];
    for (int off = 32; off; off >>= 1) contrib += __shfl_down(contrib, off);
    __shared__ float r[4];
    if ((t & 63) == 0) r[t >> 6] = contrib;
    __syncthreads();
    if (t == 0) qb[o] = r[0] + r[1] + r[2] + r[3];
  } else {
    int oo = o - 3 * C_;
    woh[oo * C_ + t] = f2bf(wo[oo * C_ + t]);
  }
}

// ---------------- 3. Transpose x[b][c][n] fp32 -> xT[b][n][c] bf16 ---------
__global__ __launch_bounds__(256) void k_transpose(const float* __restrict__ x,
                                                   u16* __restrict__ xT) {
  __shared__ float tile[64][65];
  int nb = blockIdx.x * 64, cb = blockIdx.y * 64, b = blockIdx.z;
  int t = threadIdx.x;
  int col = t & 63, rq = t >> 6;
  #pragma unroll
  for (int it = 0; it < 16; ++it) {
    int r = it * 4 + rq;
    tile[r][col] = x[((size_t)b * C_ + cb + r) * N_ + nb + col];
  }
  __syncthreads();
  #pragma unroll
  for (int it = 0; it < 16; ++it) {
    int r = it * 4 + rq;
    xT[((size_t)b * N_ + nb + r) * C_ + cb + col] = f2bf(tile[col][r]);
  }
}

// ---------------- 4. QKV GEMM ----------------------------------------------
// q is pre-scaled by d^-0.5 * log2(e) so attention softmax runs in exp2 domain.
__global__ __launch_bounds__(256) void k_qkvgemm(const u16* __restrict__ xT,
    const u16* __restrict__ wqf, const float* __restrict__ qb,
    u16* __restrict__ q, u16* __restrict__ kk, u16* __restrict__ vtt) {
  __shared__ __align__(16) u16 As[128 * 64];
  __shared__ __align__(16) u16 Bs[128 * 64];
  int b = blockIdx.y;
  int bx = blockIdx.x;
  int mt = bx % 32, ot = bx / 32;
  int mbase = mt * 128, obase = ot * 128;
  int tid = threadIdx.x, w = tid >> 6, lane = tid & 63, lg = lane >> 4, lr = lane & 15;
  int wm = w >> 1, wn = w & 1;
  f32x4 acc[4][4] = {};
  const char* asrc = (const char*)xT + ((size_t)b * N_ + mbase) * 512;
  const char* bsrc = (const char*)wqf + (size_t)obase * 512;

  for (int ks = 0; ks < 4; ++ks) {
    int kbase = ks * 64;
    #pragma unroll
    for (int rr = 0; rr < 4; ++rr) {
      int p = tid * 16 + rr * 4096;
      int row = p >> 7, col = p & 127;
      int phys = p ^ ((row & 7) << 4);
      *(bf16x8*)((char*)As + phys) = *(const bf16x8*)(asrc + (size_t)row * 512 + kbase * 2 + col);
      *(bf16x8*)((char*)Bs + phys) = *(const bf16x8*)(bsrc + (size_t)row * 512 + kbase * 2 + col);
    }
    __syncthreads();
    #pragma unroll
    for (int kc = 0; kc < 2; ++kc) {
      bf16x8 af[4], bfr[4];
      #pragma unroll
      for (int i = 0; i < 4; ++i) {
        int r = wm * 64 + i * 16 + lr;
        int L = r * 128 + kc * 64 + lg * 16;
        af[i] = *(const bf16x8*)((const char*)As + (L ^ ((r & 7) << 4)));
        int rb = wn * 64 + i * 16 + lr;
        int Lb = rb * 128 + kc * 64 + lg * 16;
        bfr[i] = *(const bf16x8*)((const char*)Bs + (Lb ^ ((rb & 7) << 4)));
      }
      #pragma unroll
      for (int i = 0; i < 4; ++i)
        #pragma unroll
        for (int jj = 0; jj < 4; ++jj)
          acc[i][jj] = mfma16(af[i], bfr[jj], acc[i][jj]);
    }
    __syncthreads();
  }

  int s_id = (obase + wn * 64) >> 8;
  int h = ((obase + wn * 64) >> 6) & 3;
  int bh = b * H_ + h;
  float scale = (s_id == 0) ? 0.18033688011112042f : 1.f;  // d^-0.5 * log2(e)
  #pragma unroll
  for (int i = 0; i < 4; ++i) {
    int n0 = mbase + wm * 64 + i * 16 + lg * 4;
    #pragma unroll
    for (int jj = 0; jj < 4; ++jj) {
      int o = obase + wn * 64 + jj * 16 + lr;
      int dd = jj * 16 + lr;
      float bias = qb[o];
      if (s_id == 2) {
        ushort4 pk;
        pk.x = f2bf(acc[i][jj][0] + bias);
        pk.y = f2bf(acc[i][jj][1] + bias);
        pk.z = f2bf(acc[i][jj][2] + bias);
        pk.w = f2bf(acc[i][jj][3] + bias);
        *(ushort4*)(vtt + ((size_t)bh * DH_ + dd) * N_ + n0) = pk;
      } else {
        u16* dst = (s_id == 0 ? q : kk) + (size_t)bh * N_ * DH_;
        #pragma unroll
        for (int r2 = 0; r2 < 4; ++r2)
          dst[(size_t)(n0 + r2) * DH_ + dd] = f2bf((acc[i][jj][r2] + bias) * scale);
      }
    }
  }
}

// ---------------- 5. Flash attention (32x32 MFMA, swapped operands) --------
// Block: 128 q-rows = 4 waves x 32 rows. KV tile = 64. Grid 512 = 2 blocks/CU.
// S^T = mfma(K, Q): lane owns q=lane&31 -> lane-local softmax (log2 domain).
// O^T = mfma(V^T, P^T): rescale + epilogue lane-local in q.
__device__ __forceinline__ void stage_tile(const char* kg_t, const char* vg_bh, int kt,
                                           char* kbuf, char* vbuf, int w, int lane) {
  #pragma unroll
  for (int i = 0; i < 2; ++i) {
    int poff = w * 2048 + i * 1024 + lane * 16;      // phys byte in 8KB tile
    int L = poff ^ (((poff >> 7) & 7) << 4);         // logical byte (involution)
    __builtin_amdgcn_global_load_lds(
        (const __attribute__((address_space(1))) void*)(kg_t + (size_t)kt * 8192 + L),
        (__attribute__((address_space(3))) void*)(kbuf + w * 2048 + i * 1024), 16, 0, 0);
    int d = L >> 7, col = L & 127;
    __builtin_amdgcn_global_load_lds(
        (const __attribute__((address_space(1))) void*)(vg_bh + (size_t)d * 8192 + (size_t)kt * 128 + col),
        (__attribute__((address_space(3))) void*)(vbuf + w * 2048 + i * 1024), 16, 0, 0);
  }
}

__global__ __launch_bounds__(256, 2) void k_attn(const u16* __restrict__ q,
    const u16* __restrict__ k, const u16* __restrict__ vt, u16* __restrict__ ao) {
  __shared__ __align__(16) char kt_s[2][8192];
  __shared__ __align__(16) char vt_s[2][8192];
  int id = blockIdx.x;
  int xcd = id & 7, j = id >> 3;      // 512 blocks: j in 0..63 per XCD
  int bh = xcd * 2 + (j >> 5);        // 2 heads per XCD -> KV L2-resident
  int qbase = (j & 31) * 128;
  int tid = threadIdx.x, w = tid >> 6, lane = tid & 63;
  int l31 = lane & 31, hi = lane >> 5;

  const char* kg_t = (const char*)(k + (size_t)bh * N_ * DH_);
  const char* vg_bh = (const char*)(vt + (size_t)bh * DH_ * N_);

  // Q B-frags: bq[cc] = Q[q=l31][c=cc*16+hi*8 ..+7]
  bf16x8 bq[4];
  {
    const u16* qp = q + ((size_t)bh * N_ + qbase + w * 32 + l31) * DH_;
    #pragma unroll
    for (int cc = 0; cc < 4; ++cc)
      bq[cc] = *(const bf16x8*)(qp + cc * 16 + hi * 8);
  }

  f32x16 Oacc0, Oacc1;
  #pragma unroll
  for (int i = 0; i < 16; ++i) { Oacc0[i] = 0.f; Oacc1[i] = 0.f; }
  float m = -1e30f, l = 0.f;

  stage_tile(kg_t, vg_bh, 0, kt_s[0], vt_s[0], w, lane);
  int cur = 0;
  for (int kt = 0; kt < N_ / 64; ++kt) {
    __syncthreads();   // staged tile visible; prev reads done
    if (kt + 1 < N_ / 64)
      stage_tile(kg_t, vg_bh, kt + 1, kt_s[cur ^ 1], vt_s[cur ^ 1], w, lane);

    const char* kb = kt_s[cur];
    const char* vb = vt_s[cur];
    bf16x8 kf[2][4], vf[2][4];
    #pragma unroll
    for (int kt2 = 0; kt2 < 2; ++kt2) {
      int row = kt2 * 32 + l31; int sw = (row & 7) << 4; int rb = row * 128;
      #pragma unroll
      for (int cc = 0; cc < 4; ++cc)
        kf[kt2][cc] = *(const bf16x8*)(kb + ((rb + cc * 32 + hi * 16) ^ sw));
    }
    #pragma unroll
    for (int dt = 0; dt < 2; ++dt) {
      int row = dt * 32 + l31; int sw = (row & 7) << 4; int rb = row * 128;
      #pragma unroll
      for (int ks = 0; ks < 4; ++ks)
        vf[dt][ks] = *(const bf16x8*)(vb + ((rb + ks * 32 + hi * 16) ^ sw));
    }

    // S^T[key][q] = K @ Q^T  (log2-domain scores)
    f32x16 s0, s1;
    #pragma unroll
    for (int i = 0; i < 16; ++i) { s0[i] = 0.f; s1[i] = 0.f; }
    __builtin_amdgcn_s_setprio(1);
    #pragma unroll
    for (int cc = 0; cc < 4; ++cc) {
      s0 = mfma32(kf[0][cc], bq[cc], s0);
      s1 = mfma32(kf[1][cc], bq[cc], s1);
    }
    __builtin_amdgcn_s_setprio(0);

    // tree local max (depth 5)
    float m8[8];
    #pragma unroll
    for (int i = 0; i < 8; ++i)
      m8[i] = fmaxf(fmaxf(s0[i], s0[i + 8]), fmaxf(s1[i], s1[i + 8]));
    float ma = fmaxf(fmaxf(m8[0], m8[1]), fmaxf(m8[2], m8[3]));
    float mb = fmaxf(fmaxf(m8[4], m8[5]), fmaxf(m8[6], m8[7]));
    float mxloc = fmaxf(ma, mb);

    // defer-max (T13): skip rescale while tile max stays within 2^8
    if (!__all(mxloc <= m + 8.f)) {
      float mx = fmaxf(mxloc, __shfl_xor(mxloc, 32));
      float mn = fmaxf(m, mx);
      float al = __builtin_amdgcn_exp2f(m - mn);
      m = mn; l *= al;
      #pragma unroll
      for (int i = 0; i < 16; ++i) { Oacc0[i] *= al; Oacc1[i] *= al; }
    }

    #pragma unroll
    for (int i = 0; i < 16; ++i) {
      s0[i] = __builtin_amdgcn_exp2f(s0[i] - m);
      s1[i] = __builtin_amdgcn_exp2f(s1[i] - m);
    }
    // tree sum (depth 5)
    float t8[8];
    #pragma unroll
    for (int i = 0; i < 8; ++i)
      t8[i] = (s0[i] + s0[i + 8]) + (s1[i] + s1[i + 8]);
    float sa = (t8[0] + t8[1]) + (t8[2] + t8[3]);
    float sb = (t8[4] + t8[5]) + (t8[6] + t8[7]);
    float sum = sa + sb;
    sum += __shfl_xor(sum, 32);
    l += sum;

    // P^T B-frags via cvt_pk + permlane32_swap (T12)
    bf16x8 pa[4];
    #pragma unroll
    for (int ks = 0; ks < 4; ++ks) {
      const int a0 = 8 * (ks & 1);
      const f32x16& sv = (ks >> 1) ? s1 : s0;
      unsigned u0 = pk2(sv[a0 + 0], sv[a0 + 1]);
      unsigned u1 = pk2(sv[a0 + 2], sv[a0 + 3]);
      unsigned u2 = pk2(sv[a0 + 4], sv[a0 + 5]);
      unsigned u3 = pk2(sv[a0 + 6], sv[a0 + 7]);
      asm("v_permlane32_swap_b32 %0, %1" : "+v"(u0), "+v"(u2));
      asm("v_permlane32_swap_b32 %0, %1" : "+v"(u1), "+v"(u3));
      union { unsigned u[4]; bf16x8 b; } cv;
      cv.u[0] = u0; cv.u[1] = u1; cv.u[2] = u2; cv.u[3] = u3;
      pa[ks] = cv.b;
    }
    // O^T += V^T @ P^T
    __builtin_amdgcn_s_setprio(1);
    #pragma unroll
    for (int ks = 0; ks < 4; ++ks) {
      Oacc0 = mfma32(vf[0][ks], pa[ks], Oacc0);
      Oacc1 = mfma32(vf[1][ks], pa[ks], Oacc1);
    }
    __builtin_amdgcn_s_setprio(0);
    cur ^= 1;
  }

  // epilogue: O^T[d][q] regs -> ao[bh][q][d] bf16
  float rl = 1.f / l;
  size_t rowb = ((size_t)bh * N_ + qbase + w * 32 + l31) * DH_;
  #pragma unroll
  for (int dt = 0; dt < 2; ++dt) {
    const f32x16& O = dt ? Oacc1 : Oacc0;
    #pragma unroll
    for (int rq = 0; rq < 4; ++rq) {
      ushort4 pk4;
      pk4.x = f2bf(O[rq * 4 + 0] * rl);
      pk4.y = f2bf(O[rq * 4 + 1] * rl);
      pk4.z = f2bf(O[rq * 4 + 2] * rl);
      pk4.w = f2bf(O[rq * 4 + 3] * rl);
      *(ushort4*)(ao + rowb + dt * 32 + rq * 8 + hi * 4) = pk4;
    }
  }
}

// ---------------- 6. Output GEMM -------------------------------------------
__global__ __launch_bounds__(256) void k_outgemm(const u16* __restrict__ ao,
    const u16* __restrict__ woh, const float* __restrict__ b_out,
    float* __restrict__ out) {
  __shared__ __align__(16) u16 As[128 * 64];
  __shared__ __align__(16) u16 Bs[128 * 64];
  int b = blockIdx.y;
  int bx = blockIdx.x;
  int mt = bx & 31, ot = bx >> 5;
  int mbase = mt * 128, obase = ot * 128;
  int tid = threadIdx.x, w = tid >> 6, lane = tid & 63, lg = lane >> 4, lr = lane & 15;
  int wm = w >> 1, wn = w & 1;
  f32x4 acc[4][4] = {};
  const char* bsrc = (const char*)woh + (size_t)obase * 512;

  for (int ks = 0; ks < 4; ++ks) {
    int kbase = ks * 64;
    int h = kbase >> 6;
    const char* asrc = (const char*)ao + ((size_t)(b * H_ + h) * N_ + mbase) * 128;
    #pragma unroll
    for (int rr = 0; rr < 4; ++rr) {
      int p = tid * 16 + rr * 4096;
      int row = p >> 7, col = p & 127;
      int phys = p ^ ((row & 7) << 4);
      *(bf16x8*)((char*)As + phys) = *(const bf16x8*)(asrc + p);
      *(bf16x8*)((char*)Bs + phys) = *(const bf16x8*)(bsrc + (size_t)row * 512 + kbase * 2 + col);
    }
    __syncthreads();
    #pragma unroll
    for (int kc = 0; kc < 2; ++kc) {
      bf16x8 af[4], bfr[4];
      #pragma unroll
      for (int i = 0; i < 4; ++i) {
        int r = wm * 64 + i * 16 + lr;
        int L = r * 128 + kc * 64 + lg * 16;
        af[i] = *(const bf16x8*)((const char*)As + (L ^ ((r & 7) << 4)));
        int rb = wn * 64 + i * 16 + lr;
        int Lb = rb * 128 + kc * 64 + lg * 16;
        bfr[i] = *(const bf16x8*)((const char*)Bs + (Lb ^ ((rb & 7) << 4)));
      }
      #pragma unroll
      for (int i = 0; i < 4; ++i)
        #pragma unroll
        for (int jj = 0; jj < 4; ++jj)
          acc[i][jj] = mfma16(af[i], bfr[jj], acc[i][jj]);
    }
    __syncthreads();
  }

  #pragma unroll
  for (int i = 0; i < 4; ++i) {
    int n0 = mbase + wm * 64 + i * 16 + lg * 4;
    #pragma unroll
    for (int jj = 0; jj < 4; ++jj) {
      int o = obase + wn * 64 + jj * 16 + lr;
      float bias = b_out[o];
      float4 vv = make_float4(acc[i][jj][0] + bias, acc[i][jj][1] + bias,
                              acc[i][jj][2] + bias, acc[i][jj][3] + bias);
      *(float4*)(out + ((size_t)(b * C_ + o)) * N_ + n0) = vv;
    }
  }
}

// ---------------- launch ----------------------------------------------------
extern "C" void kernel_launch(void* const* d_in, const int* in_sizes, int n_in,
                              void* d_out, int out_size, void* d_ws, size_t ws_size,
                              hipStream_t stream) {
  const float* x    = (const float*)d_in[0];
  const float* bnw  = (const float*)d_in[1];
  const float* bnb  = (const float*)d_in[2];
  const float* wqkv = (const float*)d_in[3];
  const float* wout = (const float*)d_in[4];
  const float* bout = (const float*)d_in[5];
  float* out = (float*)d_out;
  char* ws = (char*)d_ws;

  float* a   = (float*)(ws + 0);
  float* bb  = (float*)(ws + 1024);
  float* qb  = (float*)(ws + 2048);
  u16* wqf = (u16*)(ws + 8192);
  u16* woh = (u16*)(ws + 8192 + 393216);
  const size_t big = 8388608;
  u16* xT  = (u16*)(ws + 532480);
  u16* q   = (u16*)(ws + 532480 + 1 * big);
  u16* kk  = (u16*)(ws + 532480 + 2 * big);
  u16* vt  = (u16*)(ws + 532480 + 3 * big);
  u16* ao  = (u16*)(ws + 532480 + 4 * big);

  k_bnstats  <<<256, 256, 0, stream>>>(x, bnw, bnb, a, bb);
  k_fold     <<<1024, 256, 0, stream>>>(wqkv, wout, a, bb, wqf, qb, woh);
  k_transpose<<<dim3(64, 4, 4), 256, 0, stream>>>(x, xT);
  k_qkvgemm  <<<dim3(192, 4), 256, 0, stream>>>(xT, wqf, qb, q, kk, vt);
  k_attn     <<<dim3(512), 256, 0, stream>>>(q, kk, vt, ao);
  k_outgemm  <<<dim3(64, 4), 256, 0, stream>>>(ao, woh, bout, out);
}